// Round 11
// baseline (160.222 us; speedup 1.0000x reference)
//
#include <hip/hip_runtime.h>

#define EPS_F 1e-6f
#define BLK   256
#define TPB   512   // samples per block = 2 tiles of BLK

typedef float v4f __attribute__((ext_vector_type(4)));

// ---- Kernel 1: w = sigmoid(w_raw), 19x19 = 361 floats into d_ws ----
__global__ void sigmoid_w_kernel(const float* __restrict__ w_raw,
                                 float* __restrict__ w) {
    int i = threadIdx.x;
    if (i < 361) {
        w[i] = 1.0f / (1.0f + expf(-w_raw[i]));
    }
}

__device__ __forceinline__ float mixf(float a, float b, float wv) {
    float mn = fminf(a, b);
    float mx = fmaxf(a, b);
    return fmaf(wv, mn - mx, mx);   // w*mn + (1-w)*mx
}

__device__ __forceinline__ float clampf(float r) {
    return __builtin_amdgcn_fmed3f(r, EPS_F, 1.0f - EPS_F);  // 1-instr clamp
}

// layer-0 (tree-independent) from 5 float4 of one sample
__device__ __forceinline__ void layer0(const v4f in[5], float d[10], float mx[10]) {
    #pragma unroll
    for (int q = 0; q < 5; ++q) {
        v4f v = in[q];
        {
            float mn = fminf(v.x, v.y);
            mx[2*q] = fmaxf(v.x, v.y);
            d[2*q]  = mn - mx[2*q];
        }
        {
            float mn = fminf(v.z, v.w);
            mx[2*q+1] = fmaxf(v.z, v.w);
            d[2*q+1]  = mn - mx[2*q+1];
        }
    }
}

// all 19 trees (R0's proven paired scalar loop), results -> dst[0..18] (LDS)
__device__ __forceinline__ void trees19(const float* __restrict__ w,
                                        const float d[10], const float mx[10],
                                        float* __restrict__ dst) {
    #pragma unroll
    for (int tp = 0; tp < 9; ++tp) {
        const int t0 = 2 * tp, t1 = 2 * tp + 1;
        const float* wr0 = w + t0 * 19;
        const float* wr1 = w + t1 * 19;

        float y0[10], y1[10];
        #pragma unroll
        for (int k = 0; k < 10; ++k) {
            y0[k] = fmaf(wr0[k], d[k], mx[k]);
            y1[k] = fmaf(wr1[k], d[k], mx[k]);
        }
        float z0[5], z1[5];
        #pragma unroll
        for (int k = 0; k < 5; ++k) {
            z0[k] = mixf(y0[2*k], y0[2*k+1], wr0[10 + k]);
            z1[k] = mixf(y1[2*k], y1[2*k+1], wr1[10 + k]);
        }
        float u00 = mixf(z0[0], z0[1], wr0[15]);
        float u01 = mixf(z0[2], z0[3], wr0[16]);
        float u10 = mixf(z1[0], z1[1], wr1[15]);
        float u11 = mixf(z1[2], z1[3], wr1[16]);
        float v0 = mixf(u00, u01, wr0[17]);
        float v1 = mixf(u10, u11, wr1[17]);
        float r0 = mixf(v0, z0[4], wr0[18]);
        float r1 = mixf(v1, z1[4], wr1[18]);
        dst[t0] = clampf(r0);
        dst[t1] = clampf(r1);
    }
    {   // tree 18
        const float* wr = w + 18 * 19;
        float y[10];
        #pragma unroll
        for (int k = 0; k < 10; ++k)
            y[k] = fmaf(wr[k], d[k], mx[k]);
        float z[5];
        #pragma unroll
        for (int k = 0; k < 5; ++k)
            z[k] = mixf(y[2*k], y[2*k+1], wr[10 + k]);
        float u0 = mixf(z[0], z[1], wr[15]);
        float u1 = mixf(z[2], z[3], wr[16]);
        float v0 = mixf(u0, u1, wr[17]);
        float r  = mixf(v0, z[4], wr[18]);
        dst[18] = clampf(r);
    }
}

// wave-local coalesced nt copy-out of one wave's 64x19 region (304 float4)
__device__ __forceinline__ void waveCopyOut(const float* __restrict__ soW,
                                            float* __restrict__ out,
                                            int baseDw, int nDw, int ln) {
    const v4f* ls = reinterpret_cast<const v4f*>(soW);
    #pragma unroll
    for (int j = 0; j < 5; ++j) {
        int idx = ln + j * 64;
        if (idx < 304) {                       // j<4 always; j==4 only ln<48
            int g = baseDw + idx * 4;
            if (g + 3 < nDw) {
                __builtin_nontemporal_store(ls[idx], reinterpret_cast<v4f*>(out + g));
            } else if (g < nDw) {
                v4f t = ls[idx];
                out[g] = t.x;
                if (g + 1 < nDw) out[g + 1] = t.y;
                if (g + 2 < nDw) out[g + 2] = t.z;
            }
        }
    }
}

// ---- Kernel 2: 2-tile software pipeline per block, per-WAVE output staging,
// NO __syncthreads. Tile-B loads (issued up front) hide under tile-A compute;
// tile-A nt-stores (fire-and-forget) overlap tile-B compute. Waves march
// independently -> chip-wide read/compute/write phases mix instead of
// serializing in bursts (R10 post-mortem: phase serialization theory).
// launch_bounds(256,4): 128-VGPR budget, safely above the ~90-reg live set
// (R7/R9 lesson: never squeeze below the live set).
__global__ __launch_bounds__(BLK, 4) void tree_forward_kernel(
    const float* __restrict__ c20,   // (B, 20)
    const float* __restrict__ w,     // (19, 19) sigmoid'd
    float* __restrict__ out,         // (B, 19)
    int B)
{
    __shared__ float so[BLK * 19];   // per-wave quarters, no cross-wave sharing

    const int tid = threadIdx.x;
    const int wv  = tid >> 6;        // wave 0..3
    const int ln  = tid & 63;
    const int S0  = blockIdx.x * TPB;
    const int sA  = S0 + tid;        // tile-A sample
    const int sB  = sA + BLK;        // tile-B sample

    // Issue ALL 10 input loads up front: A's 5 first (drained first), then B's.
    v4f ia[5], ib[5];
    {
        const v4f* pA = reinterpret_cast<const v4f*>(c20 + (size_t)sA * 20);
        const v4f* pB = reinterpret_cast<const v4f*>(c20 + (size_t)sB * 20);
        const bool vA = (sA < B), vB = (sB < B);
        #pragma unroll
        for (int q = 0; q < 5; ++q) {
            v4f z; z.x = 0.f; z.y = 0.f; z.z = 0.f; z.w = 0.f;
            ia[q] = vA ? pA[q] : z;
        }
        #pragma unroll
        for (int q = 0; q < 5; ++q) {
            v4f z; z.x = 0.f; z.y = 0.f; z.z = 0.f; z.w = 0.f;
            ib[q] = vB ? pB[q] : z;
        }
    }

    float* __restrict__ o   = &so[tid * 19];        // 19-dword stride: odd ->
    const float* __restrict__ soW = &so[(wv * 64) * 19];  // 2 lanes/bank, free
    const int nDw = B * 19;

    float d[10], mx[10];

    // ---- Tile A: compute -> wave-local stage -> coalesced nt copy-out
    layer0(ia, d, mx);
    trees19(w, d, mx, o);
    __builtin_amdgcn_wave_barrier();
    asm volatile("s_waitcnt lgkmcnt(0)" ::: "memory");  // wave-local: ds_writes done
    __builtin_amdgcn_wave_barrier();
    waveCopyOut(soW, out, (S0 + wv * 64) * 19, nDw, ln);

    // ---- Tile B: same; A's stores drain in background
    layer0(ib, d, mx);
    trees19(w, d, mx, o);
    __builtin_amdgcn_wave_barrier();
    asm volatile("s_waitcnt lgkmcnt(0)" ::: "memory");
    __builtin_amdgcn_wave_barrier();
    waveCopyOut(soW, out, (S0 + BLK + wv * 64) * 19, nDw, ln);
}

extern "C" void kernel_launch(void* const* d_in, const int* in_sizes, int n_in,
                              void* d_out, int out_size, void* d_ws, size_t ws_size,
                              hipStream_t stream) {
    // setup_inputs order: p1 (B,) int, p2 (B,) int, c20 (B,20) f32, w_raw (19,19) f32
    const float* c20   = (const float*)d_in[2];
    const float* w_raw = (const float*)d_in[3];
    float* out = (float*)d_out;
    float* w   = (float*)d_ws;   // 361 floats of scratch

    int B = in_sizes[0];

    sigmoid_w_kernel<<<1, 384, 0, stream>>>(w_raw, w);

    int grid = (B + TPB - 1) / TPB;
    tree_forward_kernel<<<grid, BLK, 0, stream>>>(c20, w, out, B);
}